// Round 1
// baseline (87.927 us; speedup 1.0000x reference)
//
#include <hip/hip_runtime.h>

// Sentence_Rep: masked mean over sequence axis.
//   in : float32 [B=2048, S=200, D=300]
//   out: float32 [B, D] = sum_s(v[b,s,:] * mask[b,s]) / sum_s(mask[b,s])
//   mask[b,s] = any(v[b,s,d] != 0)
//
// Memory-bound: 491.5 MB read once, single pass. One block per batch row,
// 4 waves x 50 words each. Wave-level mask via __ballot on register-resident
// word (no syncthreads in hot loop).

#define SR_BATCH 2048
#define SR_SEQ   200
#define SR_DIM   300   // = 75 float4

__global__ __launch_bounds__(256) void sentence_rep_kernel(
    const float* __restrict__ in, float* __restrict__ out) {
    const int b    = blockIdx.x;
    const int lane = threadIdx.x & 63;
    const int wave = threadIdx.x >> 6;   // 0..3

    const float* base = in + (size_t)b * (SR_SEQ * SR_DIM);

    // Per-lane register accumulators:
    //   acc0 -> dims [4*lane, 4*lane+3]           (lanes 0..63, floats 0..255)
    //   acc1 -> dims [256+4*lane, 256+4*lane+3]   (lanes 0..10, floats 256..299)
    float a0x = 0.f, a0y = 0.f, a0z = 0.f, a0w = 0.f;
    float a1x = 0.f, a1y = 0.f, a1z = 0.f, a1w = 0.f;
    float cnt = 0.f;

    const bool has_tail = (lane < 11);   // 64 + 11 = 75 float4 = 300 floats

    for (int s = wave; s < SR_SEQ; s += 4) {
        const float4* row4 = (const float4*)(base + s * SR_DIM);
        float4 v0 = row4[lane];
        float4 v1 = make_float4(0.f, 0.f, 0.f, 0.f);
        if (has_tail) v1 = row4[64 + lane];

        bool nz = (v0.x != 0.f) | (v0.y != 0.f) | (v0.z != 0.f) | (v0.w != 0.f) |
                  (v1.x != 0.f) | (v1.y != 0.f) | (v1.z != 0.f) | (v1.w != 0.f);

        if (__ballot(nz) != 0ULL) {      // word has any nonzero component
            a0x += v0.x; a0y += v0.y; a0z += v0.z; a0w += v0.w;
            a1x += v1.x; a1y += v1.y; a1z += v1.z; a1w += v1.w;
            cnt += 1.f;
        }
    }

    // Cross-wave reduction through LDS.
    __shared__ float s_acc[4][304];      // 4 waves x 300 dims (pad to 304)
    __shared__ float s_cnt[4];

    {
        float* dst = &s_acc[wave][0];
        const int d0 = lane * 4;
        dst[d0 + 0] = a0x; dst[d0 + 1] = a0y; dst[d0 + 2] = a0z; dst[d0 + 3] = a0w;
        if (has_tail) {
            const int d1 = 256 + lane * 4;
            dst[d1 + 0] = a1x; dst[d1 + 1] = a1y; dst[d1 + 2] = a1z; dst[d1 + 3] = a1w;
        }
        if (lane == 0) s_cnt[wave] = cnt;
    }
    __syncthreads();

    const float total = s_cnt[0] + s_cnt[1] + s_cnt[2] + s_cnt[3];
    float* orow = out + (size_t)b * SR_DIM;
    for (int d = threadIdx.x; d < SR_DIM; d += 256) {
        float sum = s_acc[0][d] + s_acc[1][d] + s_acc[2][d] + s_acc[3][d];
        orow[d] = sum / total;
    }
}

extern "C" void kernel_launch(void* const* d_in, const int* in_sizes, int n_in,
                              void* d_out, int out_size, void* d_ws, size_t ws_size,
                              hipStream_t stream) {
    const float* in = (const float*)d_in[0];
    float* out = (float*)d_out;
    sentence_rep_kernel<<<SR_BATCH, 256, 0, stream>>>(in, out);
}